// Round 1
// baseline (111.384 us; speedup 1.0000x reference)
//
#include <hip/hip_runtime.h>
#include <hip/hip_fp16.h>

constexpr int T = 64, S = 32, F = 256, A = 64;
constexpr int R = T * S;  // 2048

// workspace layout (fp32 element units)
constexpr size_t OFF_XPH = 0;                           // R*A
constexpr size_t OFF_TH  = OFF_XPH + (size_t)R * A;     // R*A
constexpr size_t OFF_UU  = OFF_TH  + (size_t)R * A;     // R*A
constexpr size_t OFF_DD  = OFF_UU  + (size_t)R * A;     // R*16
constexpr size_t OFF_POS = OFF_DD  + (size_t)R * 16;    // S*S*64
constexpr size_t OFF_XGH = OFF_POS + (size_t)S * S * 64;// R*F halfs = R*F/2 floats

constexpr int XLS = 68;   // xphL row stride (floats): 16B-aligned; b128 reads hit the 2-per-quarter bank floor

__device__ __forceinline__ float dot4(float4 a, float4 b) {
    return a.x * b.x + a.y * b.y + a.z * b.z + a.w * b.w;
}
__device__ __forceinline__ float4 f4fma(float s, float4 v, float4 a) {
    a.x += s * v.x; a.y += s * v.y; a.z += s * v.z; a.w += s * v.w; return a;
}
__device__ __forceinline__ float4 f4add(float4 a, float4 b) {
    a.x += b.x; a.y += b.y; a.z += b.z; a.w += b.w; return a;
}
// 4 halfs already loaded as raw float2 -> float4
__device__ __forceinline__ float4 h4tof4(float2 raw) {
    const __half2* h = reinterpret_cast<const __half2*>(&raw);
    const float2 lo = __half22float2(h[0]);
    const float2 hi = __half22float2(h[1]);
    return make_float4(lo.x, lo.y, hi.x, hi.y);
}

// ---------------------------------------------------------------------------
// K1: blocks 0..255: 8 x-rows each (2 rows per wave):
//   th = x@Wa + ba, xph = x@WbX, uu = WbP@th, dd = Wtmp@uu
// blocks 256..511: pos projection + XG = x@WgX for 8 rows, stored fp16.
// ---------------------------------------------------------------------------
__global__ __launch_bounds__(256) void k_pre(
    const float* __restrict__ bd, const float* __restrict__ Wa,
    const float* __restrict__ ba, const float* __restrict__ Wb,
    const float* __restrict__ Wg, const float* __restrict__ Wtmp,
    const float* __restrict__ positions, const float* __restrict__ Wpos,
    const float* __restrict__ bpos,
    float* __restrict__ xph, float* __restrict__ th,
    float* __restrict__ uu, float* __restrict__ dd,
    float* __restrict__ pos, __half* __restrict__ XG_h)
{
    const int blk = blockIdx.x;
    const int tid = threadIdx.x;

    __shared__ float xs[8 * 256];
    __shared__ float ths[8][64];
    __shared__ float us[8][64];

    if (blk >= 256) {  // ---- pos + XG blocks ----
        const int xb = blk - 256;
        {   // pos: idx covers S*S*64 exactly over 256 blocks
            const int idx = xb * 256 + tid;       // (j*32+k)*64 + p
            const int p = idx & 63, jk = idx >> 6;
            const int e = p >> 5, pp = p & 31;
            const float* src = positions + (size_t)(e * 1024 + jk) * 9;
            float acc = bpos[pp];
#pragma unroll
            for (int q = 0; q < 9; ++q) acc += src[q] * Wpos[q * 32 + pp];
            pos[idx] = acc;
        }
        {   // stage 8 x-rows
            const float4* src = (const float4*)(bd + (size_t)xb * 8 * 256);
            float4* dst = (float4*)xs;
            dst[tid] = src[tid];
            dst[tid + 256] = src[tid + 256];
        }
        __syncthreads();
        // XG[r][f] = sum_c x[r][c] * WgX[c][f];  f = tid (coalesced Wg)
        float acc[8] = {0.f, 0.f, 0.f, 0.f, 0.f, 0.f, 0.f, 0.f};
#pragma unroll
        for (int c0 = 0; c0 < 256; c0 += 8) {
            float wv[8];
#pragma unroll
            for (int j = 0; j < 8; ++j) wv[j] = Wg[(size_t)(c0 + j) * 256 + tid];
#pragma unroll
            for (int j = 0; j < 8; ++j) {
#pragma unroll
                for (int r = 0; r < 8; ++r) acc[r] += xs[r * 256 + c0 + j] * wv[j];
            }
        }
#pragma unroll
        for (int r = 0; r < 8; ++r)
            XG_h[(size_t)(xb * 8 + r) * 256 + tid] = __float2half(acc[r]);
        return;
    }

    // ---- row blocks ----
    const int w = tid >> 6, lane = tid & 63;
    const int row0 = blk * 8 + 2 * w;          // this wave's two rows

    {   // stage 8 rows of x
        const float4* src = (const float4*)(bd + (size_t)blk * 8 * 256);
        float4* dst = (float4*)xs;
        dst[tid] = src[tid];
        dst[tid + 256] = src[tid + 256];
    }
    __syncthreads();

    const float* x0 = xs + (2 * w) * 256;
    const float* x1 = xs + (2 * w + 1) * 256;
    float accA0 = ba[lane], accA1 = accA0, accB0 = 0.f, accB1 = 0.f;
#pragma unroll
    for (int c0 = 0; c0 < 256; c0 += 8) {
        float wa[8], wb[8];
#pragma unroll
        for (int j = 0; j < 8; ++j) wa[j] = Wa[(c0 + j) * 64 + lane];
#pragma unroll
        for (int j = 0; j < 8; ++j) wb[j] = Wb[(c0 + j) * 64 + lane];
#pragma unroll
        for (int j = 0; j < 8; ++j) {
            const float xa = x0[c0 + j], xb2 = x1[c0 + j];
            accA0 += xa * wa[j]; accA1 += xb2 * wa[j];
            accB0 += xa * wb[j]; accB1 += xb2 * wb[j];
        }
    }
    th[(size_t)row0 * 64 + lane] = accA0;
    th[(size_t)(row0 + 1) * 64 + lane] = accA1;
    xph[(size_t)row0 * 64 + lane] = accB0;
    xph[(size_t)(row0 + 1) * 64 + lane] = accB1;
    ths[2 * w][lane] = accA0; ths[2 * w + 1][lane] = accA1;
    __syncthreads();

    float accU0 = 0.f, accU1 = 0.f;
#pragma unroll 8
    for (int a = 0; a < 64; ++a) {
        const float wp = Wb[(256 + lane) * 64 + a];
        accU0 += ths[2 * w][a] * wp;
        accU1 += ths[2 * w + 1][a] * wp;
    }
    uu[(size_t)row0 * 64 + lane] = accU0;
    uu[(size_t)(row0 + 1) * 64 + lane] = accU1;
    us[2 * w][lane] = accU0; us[2 * w + 1][lane] = accU1;
    __syncthreads();

    const int rsel = lane >> 4, q = lane & 15;
    if (rsel < 2 && q < 10) {
        float accD = 0.f;
#pragma unroll 8
        for (int p2 = 0; p2 < 64; ++p2) accD += us[2 * w + rsel][p2] * Wtmp[q * 64 + p2];
        dd[(size_t)(row0 + rsel) * 16 + q] = accD;
    }
}

// ---------------------------------------------------------------------------
// K2 (fused), v2: one block per (ss, 2 consecutive tt). 1024 blocks x 4 waves
//   = 4096 waves = 4 waves/SIMD (was 2). blockIdx = g*32 + ss so all 32
//   blocks sharing ss land on one XCD (32 % 8 == 0): temporal keys xphL
//   (16 KB), pos rows (8 KB) and temporal XG columns stay in one L2.
// Wave roles:
//   scores:  w0/w1 -> temporal row 0/1;  w2/w3 -> spatial row 0/1
//            (spatial dot split: lanes<32 do xph.th, lanes>=32 do pos.u,
//             combined with shfl_xor(32))
//   phase C: all waves temporal-xc partials (16 t each, both rows);
//            w0/w1 also gsum (row 0/1)
//   phase D: spatial-xc (w&1 = row, w>>1 = k-half) + WgP partials (p-split)
//   phase E: w0/w1 reduce + store row 0/1
// ---------------------------------------------------------------------------
__global__ __launch_bounds__(256, 4) void k_fuse(
    const float* __restrict__ temp, const float* __restrict__ Wtmp,
    const float* __restrict__ btmp, const float* __restrict__ Wg,
    const float* __restrict__ bg, const float* __restrict__ xph,
    const float* __restrict__ th, const float* __restrict__ uu,
    const float* __restrict__ dd, const float* __restrict__ pos,
    const __half* __restrict__ XG_h, float* __restrict__ out)
{
    const int ss = blockIdx.x & 31;
    const int tt0 = (blockIdx.x >> 5) * 2;
    const int tid = threadIdx.x;
    const int w = tid >> 6, lane = tid & 63;

    __shared__ float xphL[64 * XLS];      // temporal key rows (17.4 KB)
    __shared__ float th_s[2][64], u_s[2][64], d_s[2][16];
    __shared__ float es[2][32], et[2][64], w10[2][10];
    __shared__ float gs[2][64];
    __shared__ float4 zzp[4][64];         // spatial-xc partials (4 KB)
    __shared__ float4 part4[4][2][64];    // temporal-xc partials (8 KB)
    __shared__ float4 part4b[4][2][64];   // WgP partials        (8 KB)

    if (w < 2) {   // per-row vectors: wave w serves row tt0+w
        const size_t r = (size_t)(tt0 + w) * 32 + ss;
        th_s[w][lane] = th[r * 64 + lane];
        u_s[w][lane]  = uu[r * 64 + lane];
        if (lane < 16) d_s[w][lane] = dd[r * 16 + lane];
    }
    // stage temporal keys: 64 rows x 64 floats, float4 per thread x4
#pragma unroll
    for (int k2 = 0; k2 < 4; ++k2) {
        const int i = tid + 256 * k2;
        const int row = i >> 4, c = i & 15;
        const float4 v = ((const float4*)xph)[((size_t)row * 32 + ss) * 16 + c];
        *(float4*)&xphL[row * XLS + 4 * c] = v;
    }
    __syncthreads();   // A

    if (w < 2) {
        // ---- temporal scores (wave w -> row tt0+w, lane = t) ----
        const int t = lane;
        const float4* xp = (const float4*)&xphL[t * XLS];
        const float4* tv4 = (const float4*)th_s[w];
        float sc = 0.f;
#pragma unroll
        for (int a = 0; a < 16; ++a) sc += dot4(xp[a], tv4[a]);
        const float2* tp = (const float2*)(temp + (((size_t)(tt0 + w) * 64 + t) * 32 + ss) * 10);
        const float2* dv = (const float2*)d_s[w];
        float2 tmpv[5];
#pragma unroll
        for (int q = 0; q < 5; ++q) {
            tmpv[q] = tp[q];
            const float2 d2 = dv[q];
            sc += tmpv[q].x * d2.x + tmpv[q].y * d2.y;
        }
        float m = sc;
#pragma unroll
        for (int off = 32; off; off >>= 1) m = fmaxf(m, __shfl_xor(m, off));
        const float e = __expf(sc - m);
        float s = e;
#pragma unroll
        for (int off = 32; off; off >>= 1) s += __shfl_xor(s, off);
        const float at = e / s;
        et[w][t] = at;
        float r10[10];
#pragma unroll
        for (int q = 0; q < 5; ++q) { r10[2 * q] = at * tmpv[q].x; r10[2 * q + 1] = at * tmpv[q].y; }
#pragma unroll
        for (int off = 32; off; off >>= 1) {
#pragma unroll
            for (int i = 0; i < 10; ++i) r10[i] += __shfl_xor(r10[i], off);
        }
        if (lane == 0) {
#pragma unroll
            for (int i = 0; i < 10; ++i) w10[w][i] = r10[i];
        }
    } else {
        // ---- spatial scores (wave 2 -> row 0, wave 3 -> row 1) ----
        const int r = w - 2;
        const int k = lane & 31, half = lane >> 5;
        const float4* key = half
            ? (const float4*)(pos + ((size_t)ss * 32 + k) * 64)
            : (const float4*)(xph + ((size_t)(tt0 + r) * 32 + k) * 64);
        const float4* qv = half ? (const float4*)u_s[r] : (const float4*)th_s[r];
        float sc = 0.f;
#pragma unroll
        for (int a = 0; a < 16; ++a) sc += dot4(key[a], qv[a]);
        sc += __shfl_xor(sc, 32);          // combine xph.th + pos.u halves
        float m = sc;
#pragma unroll
        for (int off = 16; off; off >>= 1) m = fmaxf(m, __shfl_xor(m, off));
        const float e = __expf(sc - m);
        float s = e;
#pragma unroll
        for (int off = 16; off; off >>= 1) s += __shfl_xor(s, off);
        if (half == 0) es[r][k] = e / s;
    }
    __syncthreads();   // B

    // ---- Phase C ----
    // issue temporal-xc XG loads first (addresses are block-static; latency
    // hides under gsum)
    float2 rawT[16];
#pragma unroll
    for (int j = 0; j < 16; ++j) {
        const int t = 16 * w + j;
        rawT[j] = ((const float2*)XG_h)[((size_t)t * 32 + ss) * 64 + lane];
    }
    if (w < 2) {   // gsum (wave w -> row w, lane = p)
        const int p = lane;
        const float* pb = pos + (size_t)ss * 32 * 64 + p;
        float pv = 0.f;
#pragma unroll
        for (int k0 = 0; k0 < 32; k0 += 8) {
            float yv[8];
#pragma unroll
            for (int j = 0; j < 8; ++j) yv[j] = pb[(size_t)(k0 + j) * 64];
#pragma unroll
            for (int j = 0; j < 8; ++j) pv += es[w][k0 + j] * yv[j];
        }
        float g = pv + btmp[p];
#pragma unroll
        for (int q = 0; q < 10; ++q) g += w10[w][q] * Wtmp[q * 64 + p];
        gs[w][p] = g;
    }
    {   // temporal xc partials: wave w covers t in [16w, 16w+16), both rows
        float4 a0 = make_float4(0.f, 0.f, 0.f, 0.f), a1 = a0;
#pragma unroll
        for (int j = 0; j < 16; ++j) {
            const int t = 16 * w + j;
            const float4 x4 = h4tof4(rawT[j]);
            a0 = f4fma(et[0][t], x4, a0);
            a1 = f4fma(et[1][t], x4, a1);
        }
        part4[w][0][lane] = a0;
        part4[w][1][lane] = a1;
    }
    __syncthreads();   // C

    // ---- Phase D: spatial xc (row = w&1, k-half = w>>1) ----
    {
        const int r = w & 1, kh = (w >> 1) * 16;
        float2 rawS[16];
#pragma unroll
        for (int j = 0; j < 16; ++j)
            rawS[j] = ((const float2*)XG_h)[((size_t)(tt0 + r) * 32 + kh + j) * 64 + lane];
        float4 a = make_float4(0.f, 0.f, 0.f, 0.f);
#pragma unroll
        for (int j = 0; j < 16; ++j)
            a = f4fma(es[r][kh + j], h4tof4(rawS[j]), a);
        zzp[w][lane] = a;
    }
    // ---- Phase D: WgP partials (wave w: p in [16w,16w+16), both rows) ----
    {
        const float4* Wg4 = (const float4*)Wg;
        float4 b0 = make_float4(0.f, 0.f, 0.f, 0.f), b1 = b0;
#pragma unroll
        for (int j = 0; j < 16; ++j) {
            const int pp = 16 * w + j;
            const float4 wg = Wg4[(size_t)(256 + pp) * 64 + lane];
            b0 = f4fma(gs[0][pp], wg, b0);
            b1 = f4fma(gs[1][pp], wg, b1);
        }
        part4b[w][0][lane] = b0;
        part4b[w][1][lane] = b1;
    }
    __syncthreads();   // D

    // ---- Phase E: final reduce + store (wave w stores row tt0+w) ----
    if (w < 2) {
        float4 o = f4add(zzp[w][lane], zzp[2 + w][lane]);
#pragma unroll
        for (int w2 = 0; w2 < 4; ++w2) o = f4add(o, part4[w2][w][lane]);
#pragma unroll
        for (int w2 = 0; w2 < 4; ++w2) o = f4add(o, part4b[w2][w][lane]);
        const float4 b4 = ((const float4*)bg)[lane];
        o.x += 2.f * b4.x; o.y += 2.f * b4.y; o.z += 2.f * b4.z; o.w += 2.f * b4.w;
        ((float4*)out)[((size_t)(tt0 + w) * 32 + ss) * 64 + lane] = o;
    }
}

extern "C" void kernel_launch(void* const* d_in, const int* in_sizes, int n_in,
                              void* d_out, int out_size, void* d_ws, size_t ws_size,
                              hipStream_t stream) {
    const float* bd   = (const float*)d_in[0];
    const float* positions = (const float*)d_in[1];
    const float* temp = (const float*)d_in[2];
    const float* Wa   = (const float*)d_in[3];
    const float* ba   = (const float*)d_in[4];
    const float* Wb   = (const float*)d_in[5];
    // d_in[6] = bb: constant shift inside both softmaxes; cancels
    const float* Wg   = (const float*)d_in[7];
    const float* bg   = (const float*)d_in[8];
    const float* Wpos = (const float*)d_in[9];
    const float* bpos = (const float*)d_in[10];
    const float* Wtmp = (const float*)d_in[11];
    const float* btmp = (const float*)d_in[12];
    float* out = (float*)d_out;

    float* ws  = (float*)d_ws;
    float* xph = ws + OFF_XPH;
    float* th  = ws + OFF_TH;
    float* uu  = ws + OFF_UU;
    float* dd  = ws + OFF_DD;
    float* pos = ws + OFF_POS;
    __half* XG_h = (__half*)(ws + OFF_XGH);

    k_pre<<<512, 256, 0, stream>>>(bd, Wa, ba, Wb, Wg, Wtmp, positions, Wpos,
                                   bpos, xph, th, uu, dd, pos, XG_h);
    k_fuse<<<1024, 256, 0, stream>>>(temp, Wtmp, btmp, Wg, bg,
                                     xph, th, uu, dd, pos, XG_h, out);
}